// Round 9
// baseline (402.987 us; speedup 1.0000x reference)
//
#include <hip/hip_runtime.h>

// CubicBSplineFFD: v (4,3,42,42,42) f32 -> out (4,3,192,192,192) f32.
// Closed form after collapsing the 3 stride-5 transposed convs + crop(5,197):
//   out[m] = sum_{d=0..3} B_d(r/5) * v[a+d],  a = m/5, r = m%5   (per axis)
//
// R9 = DIAGNOSTIC ROUND. v4 (127us) and v5 (125us) are identical despite v5
// doubling occupancy and giving stores ~90% phase coverage -> every
// scheduling/locality theory is dead; some pipe is capped and the static
// model says none should be. Root issue: our ~125us dispatch has NEVER
// appeared in the rocprof top-5 (harness re-poison fills run 213-251us and
// crowd it out), so all theories were adjudicated blind on dur_us.
// This round: grid x2 with idempotent remap (bid-NBLK re-runs the same
// block: same input, byte-identical output values -> benign write-write
// races, result unchanged). Dispatch runs ~250us -> enters top-5 WITH
// counters. Accepted one-round dur_us cost (~+125us).
// Committed reads: hbm_gbps of our dispatch (~2.7 => write-path cap ->
// store shaping next; >=5 => look at VALUBusy / LDS conflicts / occupancy).
//
// Ladder (kernel time = dur - fill):
//   v0 176 | v1 146 | v2 170 | v3 181 | v4 127 | v5 125 (best, this base)

#define CPN 42
#define IMG 192
#define NTHREADS 256
#define SLICE (CPN * CPN * CPN)   // 74088
#define PLANE (CPN * CPN)         // 1764
#define NBLK (12 * IMG)           // 2304 logical blocks = (sl, x)
#define CHY 24                    // y-chunk rows
#define NCH (IMG / CHY)           // 8 chunks

typedef float v4f __attribute__((ext_vector_type(4)));

__device__ __forceinline__ float bsp_w_rt(int r, int d) {
  double f = (double)r / 5.0;
  double g = (double)(5 - r) / 5.0;
  double w;
  if (d == 0)      { w = g * g * g / 6.0; }
  else if (d == 1) { w = 2.0 / 3.0 + (0.5 * f - 1.0) * f * f; }
  else if (d == 2) { w = 2.0 / 3.0 + (0.5 * g - 1.0) * g * g; }
  else             { w = f * f * f / 6.0; }
  return (float)w;
}

__global__ void __launch_bounds__(NTHREADS) ffd_kernel(
    const float* __restrict__ v, float* __restrict__ out) {
  const int tid = threadIdx.x;
  // DIAGNOSTIC duplication: second half of the grid re-executes the same
  // logical block (idempotent; byte-identical values).
  int bid = blockIdx.x;
  if (bid >= NBLK) bid -= NBLK;
  // XCD-chunk bijection (2304 % 8 == 0): each XCD owns a contiguous
  // n-range -> contiguous ~42MB output region per XCD L2.
  const int n  = (bid & 7) * (NBLK / 8) + (bid >> 3);
  const int sl = n / IMG;          // 0..11
  const int x  = n - sl * IMG;     // 0..191
  const int ax = x / 5;            // <= 38; taps ax..ax+3 <= 41
  const int rx = x - 5 * ax;

  __shared__ v4f  wq[5];                 // weights per residue r = m%5
  __shared__ float t1[PLANE];            // x-convolved [cy][cz]   (7KB)
  __shared__ float t2c[2][CHY * CPN];    // xy-conv chunk, dbuf    (8KB)

  if (tid < 5) {
    v4f qv;
    qv.x = bsp_w_rt(tid, 0); qv.y = bsp_w_rt(tid, 1);
    qv.z = bsp_w_rt(tid, 2); qv.w = bsp_w_rt(tid, 3);
    wq[tid] = qv;
  }

  // ---- per-lane z-conv constants (register-only; verified v2..v5) ----
  const int w    = tid >> 6;
  const int lane = tid & 63;
  const int q    = lane < 48 ? lane : 47;   // lanes 48..63 clamp, no store
  const int c0   = (4 * q) / 5;             // 0..37
  float wz[4][5];
#pragma unroll
  for (int k = 0; k < 4; ++k) {
    int z = 4 * q + k;
    int c = z / 5;
    int r = z - 5 * c;
    int off = c - c0;                       // 0 or 1
#pragma unroll
    for (int t = 0; t < 5; ++t) {
      int d = t - off;
      wz[k][t] = (d >= 0 && d < 4) ? bsp_w_rt(r, d) : 0.0f;
    }
  }
  __syncthreads();                          // wq ready

  // ---- A1: x-conv. 4 contiguous 1764-float planes, coalesced, L2-hot ----
  const float* vp0 = v + (size_t)sl * SLICE + (size_t)ax * PLANE;
  const v4f wx = wq[rx];                    // wave-uniform broadcast
  for (int l = tid; l < PLANE; l += NTHREADS) {
    float a = wx.x * vp0[l];
    a = fmaf(wx.y, vp0[l + PLANE], a);
    a = fmaf(wx.z, vp0[l + 2 * PLANE], a);
    a = fmaf(wx.w, vp0[l + 3 * PLANE], a);
    t1[l] = a;
  }
  __syncthreads();

  // ---- A2 prologue: chunk 0 -> t2c[0] ----
  for (int l = tid; l < CHY * CPN; l += NTHREADS) {
    int yy = l / CPN;
    int cz = l - yy * CPN;
    int y  = yy;                            // chunk 0
    int ay = y / 5;
    int ry = y - 5 * ay;
    v4f wy = wq[ry];
    const float* tp = &t1[ay * CPN + cz];
    float a = wy.x * tp[0];
    a = fmaf(wy.y, tp[CPN], a);
    a = fmaf(wy.z, tp[2 * CPN], a);
    a = fmaf(wy.w, tp[3 * CPN], a);
    t2c[0][l] = a;
  }
  __syncthreads();

  // ---- pipeline: phase j = { B-store(chunk j) || A2(chunk j+1) } ----
  float* ob = out + (size_t)n * (IMG * IMG);
  for (int j = 0; j < NCH; ++j) {
    const float* buf = t2c[j & 1];
    // B: z-conv + dense 768B wave-stores for y in chunk j (6 y per wave)
#pragma unroll
    for (int i = 0; i < CHY / 4; ++i) {
      int yy = w + 4 * i;
      int y  = j * CHY + yy;
      const float* tp = &buf[yy * CPN + c0];
      float s0 = tp[0], s1 = tp[1], s2 = tp[2], s3 = tp[3], s4 = tp[4];
      v4f res;
#pragma unroll
      for (int k = 0; k < 4; ++k) {
        float a = wz[k][0] * s0;
        a = fmaf(wz[k][1], s1, a);
        a = fmaf(wz[k][2], s2, a);
        a = fmaf(wz[k][3], s3, a);
        a = fmaf(wz[k][4], s4, a);
        res[k] = a;
      }
      if (lane < 48)
        *reinterpret_cast<v4f*>(ob + y * IMG + 4 * q) = res;
    }
    // A2: next chunk into the other buffer (disjoint from B's reads)
    if (j + 1 < NCH) {
      float* nbuf = t2c[(j + 1) & 1];
      for (int l = tid; l < CHY * CPN; l += NTHREADS) {
        int yy = l / CPN;
        int cz = l - yy * CPN;
        int y  = (j + 1) * CHY + yy;
        int ay = y / 5;
        int ry = y - 5 * ay;
        v4f wy = wq[ry];
        const float* tp = &t1[ay * CPN + cz];
        float a = wy.x * tp[0];
        a = fmaf(wy.y, tp[CPN], a);
        a = fmaf(wy.z, tp[2 * CPN], a);
        a = fmaf(wy.w, tp[3 * CPN], a);
        nbuf[l] = a;
      }
    }
    __syncthreads();
  }
}

extern "C" void kernel_launch(void* const* d_in, const int* in_sizes, int n_in,
                              void* d_out, int out_size, void* d_ws, size_t ws_size,
                              hipStream_t stream) {
  (void)in_sizes; (void)n_in; (void)d_ws; (void)ws_size; (void)out_size;
  const float* v = (const float*)d_in[0];
  float* out = (float*)d_out;
  // DIAGNOSTIC: 2x grid, idempotent duplicate -> dispatch lands in top-5.
  ffd_kernel<<<dim3(NBLK * 2), NTHREADS, 0, stream>>>(v, out);
}